// Round 1
// baseline (32.798 us; speedup 1.0000x reference)
//
#include <hip/hip_runtime.h>
#include <math.h>

#define D 512
#define NROWS 4096
#define BATCH 16
#define CHUNKS 32           // chunks per batch
#define ROWS_PER_CHUNK 128  // NROWS / CHUNKS
#define MAIN_THREADS 512    // 8 waves
#define WAVES 8
#define ROWS_PER_WAVE 16    // ROWS_PER_CHUNK / WAVES

// workspace layout (in floats)
#define WS_PART 0            // 64*512 partial u
#define WS_U    32768        // 512
#define WS_C    33280        // 1
#define WS_RECS 33792        // 512 chunks * 514 floats
#define REC_STRIDE 514       // {m, l, p[512]}

// ---------- u = W^T v (partials, deterministic) ----------
__global__ void k_u_part(const float* __restrict__ W, const float* __restrict__ v,
                         float* __restrict__ part) {
  int g = blockIdx.x;   // 64 blocks, each 8 rows of W
  int t = threadIdx.x;  // 256 threads
  float a0 = 0.f, a1 = 0.f;
#pragma unroll
  for (int i = 0; i < 8; ++i) {
    int e = g * 8 + i;
    float ve = v[e];
    a0 = fmaf(ve, W[e * D + t], a0);
    a1 = fmaf(ve, W[e * D + t + 256], a1);
  }
  part[g * D + t] = a0;
  part[g * D + t + 256] = a1;
}

// ---------- finalize u, compute c = b . v ----------
__global__ void k_u_fin(const float* __restrict__ part, const float* __restrict__ bvec,
                        const float* __restrict__ v, float* __restrict__ u,
                        float* __restrict__ cout) {
  int t = threadIdx.x;  // 512
  float s = 0.f;
  for (int g = 0; g < 64; ++g) s += part[g * D + t];
  u[t] = s;
  __shared__ float red[512];
  red[t] = bvec[t] * v[t];
  __syncthreads();
  for (int off = 256; off > 0; off >>= 1) {
    if (t < off) red[t] += red[t + off];
    __syncthreads();
  }
  if (t == 0) cout[0] = red[0];
}

// ---------- main: per-chunk online softmax + weighted x accumulation ----------
__global__ __launch_bounds__(MAIN_THREADS) void k_main(
    const float* __restrict__ x, const int* __restrict__ mask,
    const float* __restrict__ u, const float* __restrict__ cptr,
    float* __restrict__ recs) {
  int chunk = blockIdx.x, b = blockIdx.y;
  int t = threadIdx.x;
  int lane = t & 63, w = t >> 6;

  const float4* u4 = (const float4*)u;
  float4 ua = u4[lane];        // d = 4*lane .. 4*lane+3
  float4 ub = u4[64 + lane];   // d = 256+4*lane ..
  float c = cptr[0];

  float m = -INFINITY, l = 0.f;
  float4 accA = {0.f, 0.f, 0.f, 0.f}, accB = {0.f, 0.f, 0.f, 0.f};

  int n0 = chunk * ROWS_PER_CHUNK;
  int rowbase = b * NROWS + n0;

  for (int r = 0; r < ROWS_PER_WAVE; ++r) {
    int row = rowbase + w + r * WAVES;
    if (mask[row] != 1) continue;  // masked rows: exactly zero weight; skip the load
    const float4* xp = (const float4*)x + (size_t)row * (D / 4);
    float4 a = xp[lane];
    float4 bb = xp[64 + lane];
    float s = a.x * ua.x + a.y * ua.y + a.z * ua.z + a.w * ua.w
            + bb.x * ub.x + bb.y * ub.y + bb.z * ub.z + bb.w * ub.w;
#pragma unroll
    for (int off = 32; off > 0; off >>= 1) s += __shfl_xor(s, off);
    s += c;
    float mn = fmaxf(m, s);
    float sc = __expf(m - mn);   // m==-inf -> 0
    float wg = __expf(s - mn);
    l = l * sc + wg;
    accA.x = accA.x * sc + wg * a.x;  accA.y = accA.y * sc + wg * a.y;
    accA.z = accA.z * sc + wg * a.z;  accA.w = accA.w * sc + wg * a.w;
    accB.x = accB.x * sc + wg * bb.x; accB.y = accB.y * sc + wg * bb.y;
    accB.z = accB.z * sc + wg * bb.z; accB.w = accB.w * sc + wg * bb.w;
    m = mn;
  }

  __shared__ float s_m[WAVES], s_l[WAVES];
  __shared__ float pbuf[WAVES][D];
  if (lane == 0) { s_m[w] = m; s_l[w] = l; }
  __syncthreads();

  float M = -INFINITY;
#pragma unroll
  for (int i = 0; i < WAVES; ++i) M = fmaxf(M, s_m[i]);
  float fw = (m == -INFINITY) ? 0.f : __expf(m - M);
  float4 sa = {accA.x * fw, accA.y * fw, accA.z * fw, accA.w * fw};
  float4 sb = {accB.x * fw, accB.y * fw, accB.z * fw, accB.w * fw};
  *(float4*)&pbuf[w][4 * lane] = sa;
  *(float4*)&pbuf[w][256 + 4 * lane] = sb;
  __syncthreads();

  float ltot = 0.f;
#pragma unroll
  for (int i = 0; i < WAVES; ++i) {
    float mi = s_m[i];
    float fi = (mi == -INFINITY) ? 0.f : __expf(mi - M);
    ltot += fi * s_l[i];
  }

  float* rec = recs + (size_t)(b * CHUNKS + chunk) * REC_STRIDE;
  if (t == 0) { rec[0] = M; rec[1] = ltot; }
  float sum = 0.f;
#pragma unroll
  for (int i = 0; i < WAVES; ++i) sum += pbuf[i][t];
  rec[2 + t] = sum;
}

// ---------- combine chunk partials per batch ----------
__global__ void k_combine(const float* __restrict__ recs, float* __restrict__ out) {
  int b = blockIdx.x;   // 16
  int t = threadIdx.x;  // 512
  __shared__ float sm[CHUNKS], sl[CHUNKS], sf[CHUNKS];
  if (t < CHUNKS) {
    const float* rec = recs + (size_t)(b * CHUNKS + t) * REC_STRIDE;
    sm[t] = rec[0]; sl[t] = rec[1];
  }
  __syncthreads();
  float M = -INFINITY;
#pragma unroll
  for (int i = 0; i < CHUNKS; ++i) M = fmaxf(M, sm[i]);
  if (t < CHUNKS) sf[t] = (sm[t] == -INFINITY) ? 0.f : __expf(sm[t] - M);
  __syncthreads();
  float ltot = 0.f;
#pragma unroll
  for (int i = 0; i < CHUNKS; ++i) ltot += sf[i] * sl[i];
  float o = 0.f;
  for (int i = 0; i < CHUNKS; ++i)
    o += sf[i] * recs[(size_t)(b * CHUNKS + i) * REC_STRIDE + 2 + t];
  out[b * D + t] = o / ltot;
}

extern "C" void kernel_launch(void* const* d_in, const int* in_sizes, int n_in,
                              void* d_out, int out_size, void* d_ws, size_t ws_size,
                              hipStream_t stream) {
  const float* x    = (const float*)d_in[0];
  const int*   mask = (const int*)d_in[1];
  const float* W    = (const float*)d_in[2];
  const float* bvec = (const float*)d_in[3];
  const float* v    = (const float*)d_in[4];
  float* out = (float*)d_out;
  float* ws  = (float*)d_ws;

  float* part = ws + WS_PART;
  float* u    = ws + WS_U;
  float* c    = ws + WS_C;
  float* recs = ws + WS_RECS;

  k_u_part<<<64, 256, 0, stream>>>(W, v, part);
  k_u_fin<<<1, 512, 0, stream>>>(part, bvec, v, u, c);
  dim3 g(CHUNKS, BATCH);
  k_main<<<g, MAIN_THREADS, 0, stream>>>(x, mask, u, c, recs);
  k_combine<<<BATCH, 512, 0, stream>>>(recs, out);
}